// Round 3
// baseline (377.104 us; speedup 1.0000x reference)
//
#include <hip/hip_runtime.h>
#include <math.h>

namespace {
constexpr int kB = 8;
constexpr int kC = 256;
constexpr int kH = 128;
constexpr int kW = 128;
constexpr int kHW = kH * kW;     // 16384
constexpr int kTopK = 10;
constexpr float kThreshold = 0.5f;
constexpr float kMargin = 0.5f;
constexpr float kEps = 1e-8f;
constexpr int kMaps = 2 * kB;    // 8 loc maps then 8 det maps
constexpr int kHalves = 2;       // channel halves (128 ch each)
constexpr int kTiles = 16;       // 1024-pixel tiles per map
constexpr int kStages = 16;      // 8 channels per stage
}

// ---------------------------------------------------------------------------
// Kernel 1: partial[h][m][p] = sum_{c in half h} fmap[c][p]^2.
// Block = (map, channel-half, 1024-px tile); 512 blocks x 256 (2 blocks/CU).
// Global->LDS async DMA (global_load_lds, 16B/lane): no dst VGPRs, so each
// wave issues 8 loads back-to-back -> 32 KB/stage/block guaranteed in flight
// (fixes rounds 1-2 where the compiler serialized to ~1 load/wave).
// Double-buffered 2 x 32 KB LDS; __syncthreads drains vmcnt per stage.
// ---------------------------------------------------------------------------
__global__ __launch_bounds__(256) void sumsq_kernel(
    const float* __restrict__ loc, const float* __restrict__ det,
    float* __restrict__ partial) {
  __shared__ float lds[2][8 * 1024];  // 2 x 32 KB
  const int bid = blockIdx.x;
  const int m = bid >> 5;          // map 0..15
  const int h = (bid >> 4) & 1;    // channel half
  const int tile = bid & 15;       // pixel tile
  const int t = threadIdx.x;
  const int w = t >> 6;            // wave 0..3
  const int lane = t & 63;
  const float* __restrict__ src = (m < kB) ? loc : det;
  const int b = m & (kB - 1);
  // Wave-quarter base: + channel plane offset added per issue.
  const float* gmap = src + (size_t)b * kC * kHW + (size_t)(h * 128) * kHW +
                      tile * 1024 + w * 256 + lane * 4;

  auto issue = [&](int s, int buf) {
    const float* g = gmap + (size_t)(s * 8) * kHW;
    float* l = &lds[buf][w * 256];
#pragma unroll
    for (int j = 0; j < 8; ++j) {
      __builtin_amdgcn_global_load_lds(
          (const __attribute__((address_space(1))) void*)(g + (size_t)j * kHW),
          (__attribute__((address_space(3))) void*)(l + j * 1024), 16, 0, 0);
    }
  };

  float4 acc = {0.f, 0.f, 0.f, 0.f};
  issue(0, 0);
  for (int s = 0; s < kStages; ++s) {
    __syncthreads();  // waitcnt vmcnt(0): stage-s data resident in lds[s&1]
    if (s < kStages - 1) issue(s + 1, (s + 1) & 1);  // prefetch other buffer
    const float* lb = &lds[s & 1][t * 4];
#pragma unroll
    for (int j = 0; j < 8; ++j) {
      const float4 v = *(const float4*)(lb + j * 1024);
      acc.x = fmaf(v.x, v.x, acc.x);
      acc.y = fmaf(v.y, v.y, acc.y);
      acc.z = fmaf(v.z, v.z, acc.z);
      acc.w = fmaf(v.w, v.w, acc.w);
    }
  }
  *(float4*)(partial + ((size_t)h * kMaps + m) * kHW + tile * 1024 + t * 4) =
      acc;
}

// ---------------------------------------------------------------------------
// Kernel 2: per map — phase 0 sums the 2 half-partials + sqrt -> intensity;
// then 3x3 peak mask and top-10 by value (tie -> lowest index, matching
// lax.top_k). One 1024-thread block per map; masked values in 16 regs/thread.
// ---------------------------------------------------------------------------
__global__ __launch_bounds__(1024) void topk_kernel(
    const float* __restrict__ partial, float* __restrict__ inten,
    float* __restrict__ tvals, int* __restrict__ tidx) {
  const int m = blockIdx.x;
  const int t = threadIdx.x;  // 0..1023
  float* __restrict__ I = inten + (size_t)m * kHW;

  // Phase 0: intensity = sqrt(p0 + p1), float4 per iter.
#pragma unroll
  for (int k = 0; k < 4; ++k) {
    const int p = (k * 1024 + t) * 4;
    const float* pp = partial + (size_t)m * kHW + p;
    const float4 a = *(const float4*)(pp);
    const float4 q = *(const float4*)(pp + (size_t)kMaps * kHW);
    float4 o = {sqrtf(a.x + q.x), sqrtf(a.y + q.y), sqrtf(a.z + q.z),
                sqrtf(a.w + q.w)};
    *(float4*)(I + p) = o;
  }
  __syncthreads();

  // Phase 1: masked peak values, pixel p = k*1024 + t.
  float v[16];
#pragma unroll
  for (int k = 0; k < 16; ++k) {
    const int p = k * 1024 + t;
    const int y = p >> 7;
    const int x = p & (kW - 1);
    const float c0 = I[p];
    float nmax = -INFINITY;
    for (int dy = -1; dy <= 1; ++dy) {
      const int yy = y + dy;
      if (yy < 0 || yy >= kH) continue;
      for (int dx = -1; dx <= 1; ++dx) {
        const int xx = x + dx;
        if (xx < 0 || xx >= kW) continue;
        nmax = fmaxf(nmax, I[yy * kW + xx]);
      }
    }
    const bool peak = (c0 > kThreshold) && (c0 >= nmax);
    v[k] = peak ? c0 : -INFINITY;
  }

  // Phase 2: 10 rounds of block-wide argmax with removal.
  __shared__ float s_wv[16];
  __shared__ int s_wi[16];
  __shared__ int s_bi;
  const int wave = t >> 6;
  const int lane = t & 63;

  for (int r = 0; r < kTopK; ++r) {
    float bv = v[0];
    int bi = t;
#pragma unroll
    for (int k = 1; k < 16; ++k) {
      const int idx = k * 1024 + t;
      if (v[k] > bv || (v[k] == bv && idx < bi)) { bv = v[k]; bi = idx; }
    }
    for (int off = 32; off > 0; off >>= 1) {
      const float ov = __shfl_down(bv, off, 64);
      const int oi = __shfl_down(bi, off, 64);
      if (ov > bv || (ov == bv && oi < bi)) { bv = ov; bi = oi; }
    }
    if (lane == 0) { s_wv[wave] = bv; s_wi[wave] = bi; }
    __syncthreads();
    if (t == 0) {
      float xv = s_wv[0];
      int xi = s_wi[0];
      for (int w2 = 1; w2 < 16; ++w2) {
        if (s_wv[w2] > xv || (s_wv[w2] == xv && s_wi[w2] < xi)) {
          xv = s_wv[w2];
          xi = s_wi[w2];
        }
      }
      s_bi = xi;
      tvals[m * kTopK + r] = xv;
      tidx[m * kTopK + r] = xi;
    }
    __syncthreads();
    const int wi = s_bi;
    if ((wi & 1023) == t) v[wi >> 10] = -INFINITY;
    __syncthreads();
  }
}

// ---------------------------------------------------------------------------
// Kernel 3: per sample, gather [10,256] det & loc peak features, compute
// 10x10 cosine sims (norm == top-k intensity value), masked hinge mean.
// 8 blocks x 256 threads (thread = channel). LDS rows padded to 257 floats.
// ---------------------------------------------------------------------------
__global__ __launch_bounds__(256) void loss_kernel(
    const float* __restrict__ loc, const float* __restrict__ det,
    const float* __restrict__ tvals, const int* __restrict__ tidx,
    float* __restrict__ losses) {
  const int b = blockIdx.x;
  const int t = threadIdx.x;  // channel
  __shared__ float ds[kTopK][kC + 1];
  __shared__ float ls[kTopK][kC + 1];
  __shared__ float s_red[kC];

  float lv[kTopK], dv[kTopK];
  int li[kTopK], di[kTopK];
#pragma unroll
  for (int i = 0; i < kTopK; ++i) {
    lv[i] = tvals[b * kTopK + i];
    li[i] = tidx[b * kTopK + i];
    dv[i] = tvals[(kB + b) * kTopK + i];
    di[i] = tidx[(kB + b) * kTopK + i];
  }
  const float* lb = loc + (size_t)b * kC * kHW + (size_t)t * kHW;
  const float* db = det + (size_t)b * kC * kHW + (size_t)t * kHW;
#pragma unroll
  for (int i = 0; i < kTopK; ++i) {
    ls[i][t] = lb[li[i]];
    ds[i][t] = db[di[i]];
  }
  __syncthreads();

  float contrib = 0.f;
  if (t < kTopK * kTopK) {
    const int i = t / kTopK;  // det peak
    const int j = t % kTopK;  // loc peak
    const bool valid = (dv[i] > -1e30f) && (lv[j] > -1e30f);
    if (valid) {
      float dot = 0.f;
#pragma unroll 8
      for (int c = 0; c < kC; ++c) dot = fmaf(ds[i][c], ls[j][c], dot);
      const float na = fmaxf(dv[i], kEps);
      const float nb = fmaxf(lv[j], kEps);
      const float sim = dot / (na * nb);
      contrib = fmaxf(sim - kMargin, 0.f);
    }
  }
  s_red[t] = contrib;
  __syncthreads();
  if (t == 0) {
    int nd = 0, nl = 0;
    for (int i = 0; i < kTopK; ++i) {
      nd += (dv[i] > -1e30f) ? 1 : 0;
      nl += (lv[i] > -1e30f) ? 1 : 0;
    }
    float s = 0.f;
    for (int k = 0; k < kTopK * kTopK; ++k) s += s_red[k];
    const int np = nd * nl;
    losses[b] = (np > 0) ? (s / (float)np) : 0.f;
  }
}

// ---------------------------------------------------------------------------
// Kernel 4: mean over batch.
// ---------------------------------------------------------------------------
__global__ void final_kernel(const float* __restrict__ losses,
                             float* __restrict__ out) {
  if (threadIdx.x == 0 && blockIdx.x == 0) {
    float s = 0.f;
    for (int i = 0; i < kB; ++i) s += losses[i];
    out[0] = s / (float)kB;
  }
}

extern "C" void kernel_launch(void* const* d_in, const int* in_sizes, int n_in,
                              void* d_out, int out_size, void* d_ws,
                              size_t ws_size, hipStream_t stream) {
  const float* loc = (const float*)d_in[0];
  const float* det = (const float*)d_in[1];
  float* out = (float*)d_out;

  // Workspace (floats): partial [2*16*16384] (2 MB) | inten [16*16384]
  // (1 MB) | tvals [160] | tidx [160 ints] | losses [8]  -> ~3 MB total.
  float* wsf = (float*)d_ws;
  float* partial = wsf;
  float* inten = partial + (size_t)kHalves * kMaps * kHW;
  float* tvals = inten + (size_t)kMaps * kHW;
  int* tidx = (int*)(tvals + kMaps * kTopK);
  float* losses = (float*)(tidx + kMaps * kTopK);

  sumsq_kernel<<<dim3(kMaps * kHalves * kTiles), dim3(256), 0, stream>>>(
      loc, det, partial);
  topk_kernel<<<dim3(kMaps), dim3(1024), 0, stream>>>(partial, inten, tvals,
                                                      tidx);
  loss_kernel<<<dim3(kB), dim3(kC), 0, stream>>>(loc, det, tvals, tidx,
                                                 losses);
  final_kernel<<<dim3(1), dim3(64), 0, stream>>>(losses, out);
}

// Round 4
// 357.356 us; speedup vs baseline: 1.0553x; 1.0553x over previous
//
#include <hip/hip_runtime.h>
#include <math.h>

namespace {
constexpr int kB = 8;
constexpr int kC = 256;
constexpr int kH = 128;
constexpr int kW = 128;
constexpr int kHW = kH * kW;     // 16384
constexpr int kTopK = 10;
constexpr float kThreshold = 0.5f;
constexpr float kMargin = 0.5f;
constexpr float kEps = 1e-8f;
constexpr int kMaps = 2 * kB;    // 8 loc maps then 8 det maps
constexpr int kChunks = 8;       // channel chunks (32 ch each)
constexpr int kCPer = kC / kChunks;
constexpr int kSegs = 16;        // pixel segments (1024 px each)
constexpr int kSegPx = kHW / kSegs;
}

// ---------------------------------------------------------------------------
// Kernel 1: partial[ch][m][p] = sum_{c in chunk ch} fmap[c][p]^2.
// 2048 blocks x 256 = 32 waves/CU (the HW cap) -- rounds 1-3 were all
// grid-capped at 8-16 waves/CU and flatlined at ~8.4 GB/s/CU; this round
// tests the TLP theory. VGPR kept <=64 via launch_bounds so occupancy is
// grid-limited only. 8-deep float4 load batch per iteration.
// ---------------------------------------------------------------------------
__global__ __launch_bounds__(256, 8) void sumsq_kernel(
    const float* __restrict__ loc, const float* __restrict__ det,
    float* __restrict__ partial) {
  const int bid = blockIdx.x;      // 0..2047
  const int m = bid >> 7;          // map 0..15 (128 blocks per map)
  const int r = bid & 127;
  const int ch = r >> 4;           // chunk 0..7
  const int seg = r & 15;          // segment 0..15
  const int t = threadIdx.x;
  const float* __restrict__ src = (m < kB) ? loc : det;
  const int b = m & (kB - 1);
  const float* base = src + (size_t)b * kC * kHW +
                      (size_t)(ch * kCPer) * kHW + seg * kSegPx + t * 4;
  float4 acc = {0.f, 0.f, 0.f, 0.f};
  for (int c0 = 0; c0 < kCPer; c0 += 8) {
    float4 v[8];
#pragma unroll
    for (int j = 0; j < 8; ++j)
      v[j] = *(const float4*)(base + (size_t)(c0 + j) * kHW);
#pragma unroll
    for (int j = 0; j < 8; ++j) {
      acc.x = fmaf(v[j].x, v[j].x, acc.x);
      acc.y = fmaf(v[j].y, v[j].y, acc.y);
      acc.z = fmaf(v[j].z, v[j].z, acc.z);
      acc.w = fmaf(v[j].w, v[j].w, acc.w);
    }
  }
  *(float4*)(partial + ((size_t)ch * kMaps + m) * kHW + seg * kSegPx +
             t * 4) = acc;
}

// ---------------------------------------------------------------------------
// Kernel 2: inten[m][p] = sqrt(sum_ch partial[ch][m][p]).
// 256 blocks x 256, one float4 per thread, 8 strided reads each. Keeps the
// 8 MB partial-combine OFF the 16-block topk kernel's critical path.
// ---------------------------------------------------------------------------
__global__ __launch_bounds__(256) void combine_kernel(
    const float* __restrict__ partial, float* __restrict__ inten) {
  const int g = blockIdx.x * 256 + threadIdx.x;  // float4 group 0..65535
  const int m = g >> 12;                         // 4096 groups per map
  const int p = (g & 4095) * 4;
  const float* pp = partial + (size_t)m * kHW + p;
  float4 s = *(const float4*)(pp);
#pragma unroll
  for (int ch = 1; ch < kChunks; ++ch) {
    const float4 q = *(const float4*)(pp + (size_t)ch * kMaps * kHW);
    s.x += q.x; s.y += q.y; s.z += q.z; s.w += q.w;
  }
  float4 o = {sqrtf(s.x), sqrtf(s.y), sqrtf(s.z), sqrtf(s.w)};
  *(float4*)(inten + (size_t)m * kHW + p) = o;
}

// ---------------------------------------------------------------------------
// Kernel 3: per map, 3x3 peak mask (> 0.5) then top-10 by value
// (tie -> lowest index, matching lax.top_k). One 1024-thread block per map;
// masked values in 16 regs/thread; inten (64 KB/map) served from L1/L2.
// ---------------------------------------------------------------------------
__global__ __launch_bounds__(1024) void topk_kernel(
    const float* __restrict__ inten, float* __restrict__ tvals,
    int* __restrict__ tidx) {
  const int m = blockIdx.x;
  const int t = threadIdx.x;  // 0..1023
  const float* __restrict__ I = inten + (size_t)m * kHW;

  float v[16];
#pragma unroll
  for (int k = 0; k < 16; ++k) {
    const int p = k * 1024 + t;
    const int y = p >> 7;
    const int x = p & (kW - 1);
    const float c0 = I[p];
    float nmax = -INFINITY;
    for (int dy = -1; dy <= 1; ++dy) {
      const int yy = y + dy;
      if (yy < 0 || yy >= kH) continue;
      for (int dx = -1; dx <= 1; ++dx) {
        const int xx = x + dx;
        if (xx < 0 || xx >= kW) continue;
        nmax = fmaxf(nmax, I[yy * kW + xx]);
      }
    }
    const bool peak = (c0 > kThreshold) && (c0 >= nmax);
    v[k] = peak ? c0 : -INFINITY;
  }

  __shared__ float s_wv[16];
  __shared__ int s_wi[16];
  __shared__ int s_bi;
  const int wave = t >> 6;
  const int lane = t & 63;

  for (int r = 0; r < kTopK; ++r) {
    float bv = v[0];
    int bi = t;
#pragma unroll
    for (int k = 1; k < 16; ++k) {
      const int idx = k * 1024 + t;
      if (v[k] > bv || (v[k] == bv && idx < bi)) { bv = v[k]; bi = idx; }
    }
    for (int off = 32; off > 0; off >>= 1) {
      const float ov = __shfl_down(bv, off, 64);
      const int oi = __shfl_down(bi, off, 64);
      if (ov > bv || (ov == bv && oi < bi)) { bv = ov; bi = oi; }
    }
    if (lane == 0) { s_wv[wave] = bv; s_wi[wave] = bi; }
    __syncthreads();
    if (t == 0) {
      float xv = s_wv[0];
      int xi = s_wi[0];
      for (int w2 = 1; w2 < 16; ++w2) {
        if (s_wv[w2] > xv || (s_wv[w2] == xv && s_wi[w2] < xi)) {
          xv = s_wv[w2];
          xi = s_wi[w2];
        }
      }
      s_bi = xi;
      tvals[m * kTopK + r] = xv;
      tidx[m * kTopK + r] = xi;
    }
    __syncthreads();
    const int wi = s_bi;
    if ((wi & 1023) == t) v[wi >> 10] = -INFINITY;
    __syncthreads();
  }
}

// ---------------------------------------------------------------------------
// Kernel 4: per sample, gather [10,256] det & loc peak features, compute
// 10x10 cosine sims (norm == top-k intensity value), masked hinge mean.
// 8 blocks x 256 threads (thread = channel). LDS rows padded to 257 floats.
// ---------------------------------------------------------------------------
__global__ __launch_bounds__(256) void loss_kernel(
    const float* __restrict__ loc, const float* __restrict__ det,
    const float* __restrict__ tvals, const int* __restrict__ tidx,
    float* __restrict__ losses) {
  const int b = blockIdx.x;
  const int t = threadIdx.x;  // channel
  __shared__ float ds[kTopK][kC + 1];
  __shared__ float ls[kTopK][kC + 1];
  __shared__ float s_red[kC];

  float lv[kTopK], dv[kTopK];
  int li[kTopK], di[kTopK];
#pragma unroll
  for (int i = 0; i < kTopK; ++i) {
    lv[i] = tvals[b * kTopK + i];
    li[i] = tidx[b * kTopK + i];
    dv[i] = tvals[(kB + b) * kTopK + i];
    di[i] = tidx[(kB + b) * kTopK + i];
  }
  const float* lb = loc + (size_t)b * kC * kHW + (size_t)t * kHW;
  const float* db = det + (size_t)b * kC * kHW + (size_t)t * kHW;
#pragma unroll
  for (int i = 0; i < kTopK; ++i) {
    ls[i][t] = lb[li[i]];
    ds[i][t] = db[di[i]];
  }
  __syncthreads();

  float contrib = 0.f;
  if (t < kTopK * kTopK) {
    const int i = t / kTopK;  // det peak
    const int j = t % kTopK;  // loc peak
    const bool valid = (dv[i] > -1e30f) && (lv[j] > -1e30f);
    if (valid) {
      float dot = 0.f;
#pragma unroll 8
      for (int c = 0; c < kC; ++c) dot = fmaf(ds[i][c], ls[j][c], dot);
      const float na = fmaxf(dv[i], kEps);
      const float nb = fmaxf(lv[j], kEps);
      const float sim = dot / (na * nb);
      contrib = fmaxf(sim - kMargin, 0.f);
    }
  }
  s_red[t] = contrib;
  __syncthreads();
  if (t == 0) {
    int nd = 0, nl = 0;
    for (int i = 0; i < kTopK; ++i) {
      nd += (dv[i] > -1e30f) ? 1 : 0;
      nl += (lv[i] > -1e30f) ? 1 : 0;
    }
    float s = 0.f;
    for (int k = 0; k < kTopK * kTopK; ++k) s += s_red[k];
    const int np = nd * nl;
    losses[b] = (np > 0) ? (s / (float)np) : 0.f;
  }
}

// ---------------------------------------------------------------------------
// Kernel 5: mean over batch.
// ---------------------------------------------------------------------------
__global__ void final_kernel(const float* __restrict__ losses,
                             float* __restrict__ out) {
  if (threadIdx.x == 0 && blockIdx.x == 0) {
    float s = 0.f;
    for (int i = 0; i < kB; ++i) s += losses[i];
    out[0] = s / (float)kB;
  }
}

extern "C" void kernel_launch(void* const* d_in, const int* in_sizes, int n_in,
                              void* d_out, int out_size, void* d_ws,
                              size_t ws_size, hipStream_t stream) {
  const float* loc = (const float*)d_in[0];
  const float* det = (const float*)d_in[1];
  float* out = (float*)d_out;

  // Workspace (floats): partial [8*16*16384] (8 MB) | inten [16*16384]
  // (1 MB) | tvals [160] | tidx [160 ints] | losses [8]  -> ~9 MB total.
  float* wsf = (float*)d_ws;
  float* partial = wsf;
  float* inten = partial + (size_t)kChunks * kMaps * kHW;
  float* tvals = inten + (size_t)kMaps * kHW;
  int* tidx = (int*)(tvals + kMaps * kTopK);
  float* losses = (float*)(tidx + kMaps * kTopK);

  sumsq_kernel<<<dim3(kMaps * kChunks * kSegs), dim3(256), 0, stream>>>(
      loc, det, partial);
  combine_kernel<<<dim3(kMaps * kHW / 4 / 256), dim3(256), 0, stream>>>(
      partial, inten);
  topk_kernel<<<dim3(kMaps), dim3(1024), 0, stream>>>(inten, tvals, tidx);
  loss_kernel<<<dim3(kB), dim3(kC), 0, stream>>>(loc, det, tvals, tidx,
                                                 losses);
  final_kernel<<<dim3(1), dim3(64), 0, stream>>>(losses, out);
}

// Round 5
// 345.108 us; speedup vs baseline: 1.0927x; 1.0355x over previous
//
#include <hip/hip_runtime.h>
#include <math.h>

namespace {
constexpr int kB = 8;
constexpr int kC = 256;
constexpr int kH = 128;
constexpr int kW = 128;
constexpr int kHW = kH * kW;     // 16384
constexpr int kTopK = 10;
constexpr float kThreshold = 0.5f;
constexpr float kMargin = 0.5f;
constexpr float kEps = 1e-8f;
constexpr int kMaps = 2 * kB;            // 8 loc maps then 8 det maps
constexpr int kGrpPlanes = 16;           // channel planes per block (1 MB)
constexpr int kGroups = kC / kGrpPlanes; // 16 groups per map
}

// ---------------------------------------------------------------------------
// Kernel 1: partial[m][g][p] = sum_{c in group g} fmap[c][p]^2.
// CONTIGUITY EXPERIMENT: each block linearly sweeps a contiguous 1 MB span
// (16 whole 64 KB channel planes of one map) — rounds 1-4 all read 1-4 KB
// chunks at 64 KB stride and converged at 2.2-2.6 TB/s regardless of wave
// count / MLP depth / DMA. Per-pixel accumulation lives in a 64 KB LDS
// buffer; wave w owns pixels [w*2048,(w+1)*2048) so the LDS RMW is
// race-free with no barriers. sched_barrier(0) pins the 8-deep load batch
// (R4: allocator serialized batches down to VGPR=32).
// 256 blocks x 512 threads = 8 waves/CU.
// ---------------------------------------------------------------------------
__global__ __launch_bounds__(512) void sumsq_kernel(
    const float* __restrict__ loc, const float* __restrict__ det,
    float* __restrict__ partial) {
  __shared__ float acc[kHW];  // 64 KB per-block pixel accumulator
  const int bid = blockIdx.x;
  const int m = bid >> 4;   // map 0..15
  const int g = bid & 15;   // plane group 0..15
  const int t = threadIdx.x;
  const int w = t >> 6;     // wave 0..7
  const int lane = t & 63;
  const float* __restrict__ src = (m < kB) ? loc : det;
  const int b = m & (kB - 1);
  const float* base = src + (size_t)b * kC * kHW +
                      (size_t)(g * kGrpPlanes) * kHW + w * 2048 + lane * 4;
  float* lacc = acc + w * 2048 + lane * 4;

  // Plane 0: initialize LDS accumulator.
  {
    float4 v[8];
#pragma unroll
    for (int i = 0; i < 8; ++i) v[i] = *(const float4*)(base + i * 256);
    __builtin_amdgcn_sched_barrier(0);  // all 8 loads issue before any use
#pragma unroll
    for (int i = 0; i < 8; ++i) {
      float4 o;
      o.x = v[i].x * v[i].x;
      o.y = v[i].y * v[i].y;
      o.z = v[i].z * v[i].z;
      o.w = v[i].w * v[i].w;
      *(float4*)(lacc + i * 256) = o;
    }
  }
  // Planes 1..15: accumulate.
  for (int j = 1; j < kGrpPlanes; ++j) {
    const float* pb = base + (size_t)j * kHW;
    float4 v[8];
#pragma unroll
    for (int i = 0; i < 8; ++i) v[i] = *(const float4*)(pb + i * 256);
    __builtin_amdgcn_sched_barrier(0);
#pragma unroll
    for (int i = 0; i < 8; ++i) {
      float4 a = *(const float4*)(lacc + i * 256);
      a.x = fmaf(v[i].x, v[i].x, a.x);
      a.y = fmaf(v[i].y, v[i].y, a.y);
      a.z = fmaf(v[i].z, v[i].z, a.z);
      a.w = fmaf(v[i].w, v[i].w, a.w);
      *(float4*)(lacc + i * 256) = a;
    }
  }
  // Dump the wave-private eighth to the block's partial (coalesced 1 KB/inst).
  float* out = partial + ((size_t)m * kGroups + g) * kHW + w * 2048 + lane * 4;
#pragma unroll
  for (int i = 0; i < 8; ++i)
    *(float4*)(out + i * 256) = *(const float4*)(lacc + i * 256);
}

// ---------------------------------------------------------------------------
// Kernel 2: inten[m][p] = sqrt(sum_g partial[m][g][p]).  16 MB read,
// 256 blocks x 256 threads, one float4/thread, 16 strided reads.
// ---------------------------------------------------------------------------
__global__ __launch_bounds__(256) void combine_kernel(
    const float* __restrict__ partial, float* __restrict__ inten) {
  const int gi = blockIdx.x * 256 + threadIdx.x;  // float4 group 0..65535
  const int m = gi >> 12;
  const int p = (gi & 4095) * 4;
  const float* pp = partial + (size_t)m * kGroups * kHW + p;
  float4 s = {0.f, 0.f, 0.f, 0.f};
#pragma unroll
  for (int g = 0; g < kGroups; ++g) {
    const float4 q = *(const float4*)(pp + (size_t)g * kHW);
    s.x += q.x;
    s.y += q.y;
    s.z += q.z;
    s.w += q.w;
  }
  float4 o = {sqrtf(s.x), sqrtf(s.y), sqrtf(s.z), sqrtf(s.w)};
  *(float4*)(inten + (size_t)m * kHW + p) = o;
}

// ---------------------------------------------------------------------------
// Kernel 3: per map, 3x3 peak mask (> 0.5) then top-10 by value (tie ->
// lowest index, matching lax.top_k). Rewritten: per-wave top-10 via
// shfl_xor butterfly (barrier-free), then one wave merges the 160
// candidates. One __syncthreads total (was ~30).
// ---------------------------------------------------------------------------
__global__ __launch_bounds__(1024) void topk_kernel(
    const float* __restrict__ inten, float* __restrict__ tvals,
    int* __restrict__ tidx) {
  const int m = blockIdx.x;
  const int t = threadIdx.x;  // 0..1023
  const int w = t >> 6;
  const int lane = t & 63;
  const float* __restrict__ I = inten + (size_t)m * kHW;

  // Masked peak values, pixel p = k*1024 + t.
  float v[16];
#pragma unroll
  for (int k = 0; k < 16; ++k) {
    const int p = k * 1024 + t;
    const int y = p >> 7;
    const int x = p & (kW - 1);
    const float c0 = I[p];
    float nmax = -INFINITY;
    for (int dy = -1; dy <= 1; ++dy) {
      const int yy = y + dy;
      if (yy < 0 || yy >= kH) continue;
      for (int dx = -1; dx <= 1; ++dx) {
        const int xx = x + dx;
        if (xx < 0 || xx >= kW) continue;
        nmax = fmaxf(nmax, I[yy * kW + xx]);
      }
    }
    const bool peak = (c0 > kThreshold) && (c0 >= nmax);
    v[k] = peak ? c0 : -INFINITY;
  }

  // Per-wave top-10 (butterfly argmax with removal; all lanes see winner).
  __shared__ float swv[16][kTopK];
  __shared__ int swi[16][kTopK];
  for (int r = 0; r < kTopK; ++r) {
    float bv = v[0];
    int bi = t;  // pixel index of k=0 element is 0*1024 + t
#pragma unroll
    for (int k = 1; k < 16; ++k) {
      const int idx = k * 1024 + t;
      if (v[k] > bv || (v[k] == bv && idx < bi)) { bv = v[k]; bi = idx; }
    }
    for (int off = 1; off < 64; off <<= 1) {
      const float ov = __shfl_xor(bv, off, 64);
      const int oi = __shfl_xor(bi, off, 64);
      if (ov > bv || (ov == bv && oi < bi)) { bv = ov; bi = oi; }
    }
    if (lane == r) { swv[w][r] = bv; swi[w][r] = bi; }
    if ((bi & 1023) == t) v[bi >> 10] = -INFINITY;  // owner clears winner
  }
  __syncthreads();

  // Wave 0 merges the 16 waves' lists (160 candidates, 3 slots/lane).
  if (w == 0) {
    float cv[3];
    int ci[3];
#pragma unroll
    for (int q = 0; q < 3; ++q) {
      const int s = lane + 64 * q;
      if (s < 16 * kTopK) {
        cv[q] = swv[s / kTopK][s % kTopK];
        ci[q] = swi[s / kTopK][s % kTopK];
      } else {
        cv[q] = -INFINITY;
        ci[q] = 0x7fffffff;
      }
    }
    for (int r = 0; r < kTopK; ++r) {
      float bv = cv[0];
      int bi = ci[0];
#pragma unroll
      for (int q = 1; q < 3; ++q)
        if (cv[q] > bv || (cv[q] == bv && ci[q] < bi)) { bv = cv[q]; bi = ci[q]; }
      for (int off = 1; off < 64; off <<= 1) {
        const float ov = __shfl_xor(bv, off, 64);
        const int oi = __shfl_xor(bi, off, 64);
        if (ov > bv || (ov == bv && oi < bi)) { bv = ov; bi = oi; }
      }
      if (lane == r) {
        tvals[m * kTopK + r] = bv;
        tidx[m * kTopK + r] = bi;
      }
#pragma unroll
      for (int q = 0; q < 3; ++q)
        if (ci[q] == bi) { cv[q] = -INFINITY; ci[q] = 0x7fffffff; }
    }
  }
}

// ---------------------------------------------------------------------------
// Kernel 4: per sample, gather [10,256] det & loc peak features, compute
// 10x10 cosine sims (norm == top-k intensity value), masked hinge mean.
// ---------------------------------------------------------------------------
__global__ __launch_bounds__(256) void loss_kernel(
    const float* __restrict__ loc, const float* __restrict__ det,
    const float* __restrict__ tvals, const int* __restrict__ tidx,
    float* __restrict__ losses) {
  const int b = blockIdx.x;
  const int t = threadIdx.x;  // channel
  __shared__ float ds[kTopK][kC + 1];
  __shared__ float ls[kTopK][kC + 1];
  __shared__ float s_red[kC];

  float lv[kTopK], dv[kTopK];
  int li[kTopK], di[kTopK];
#pragma unroll
  for (int i = 0; i < kTopK; ++i) {
    lv[i] = tvals[b * kTopK + i];
    li[i] = tidx[b * kTopK + i];
    dv[i] = tvals[(kB + b) * kTopK + i];
    di[i] = tidx[(kB + b) * kTopK + i];
  }
  const float* lb = loc + (size_t)b * kC * kHW + (size_t)t * kHW;
  const float* db = det + (size_t)b * kC * kHW + (size_t)t * kHW;
#pragma unroll
  for (int i = 0; i < kTopK; ++i) {
    ls[i][t] = lb[li[i]];
    ds[i][t] = db[di[i]];
  }
  __syncthreads();

  float contrib = 0.f;
  if (t < kTopK * kTopK) {
    const int i = t / kTopK;  // det peak
    const int j = t % kTopK;  // loc peak
    const bool valid = (dv[i] > -1e30f) && (lv[j] > -1e30f);
    if (valid) {
      float dot = 0.f;
#pragma unroll 8
      for (int c = 0; c < kC; ++c) dot = fmaf(ds[i][c], ls[j][c], dot);
      const float na = fmaxf(dv[i], kEps);
      const float nb = fmaxf(lv[j], kEps);
      const float sim = dot / (na * nb);
      contrib = fmaxf(sim - kMargin, 0.f);
    }
  }
  s_red[t] = contrib;
  __syncthreads();
  if (t == 0) {
    int nd = 0, nl = 0;
    for (int i = 0; i < kTopK; ++i) {
      nd += (dv[i] > -1e30f) ? 1 : 0;
      nl += (lv[i] > -1e30f) ? 1 : 0;
    }
    float s = 0.f;
    for (int k = 0; k < kTopK * kTopK; ++k) s += s_red[k];
    const int np = nd * nl;
    losses[b] = (np > 0) ? (s / (float)np) : 0.f;
  }
}

// ---------------------------------------------------------------------------
// Kernel 5: mean over batch.
// ---------------------------------------------------------------------------
__global__ void final_kernel(const float* __restrict__ losses,
                             float* __restrict__ out) {
  if (threadIdx.x == 0 && blockIdx.x == 0) {
    float s = 0.f;
    for (int i = 0; i < kB; ++i) s += losses[i];
    out[0] = s / (float)kB;
  }
}

extern "C" void kernel_launch(void* const* d_in, const int* in_sizes, int n_in,
                              void* d_out, int out_size, void* d_ws,
                              size_t ws_size, hipStream_t stream) {
  const float* loc = (const float*)d_in[0];
  const float* det = (const float*)d_in[1];
  float* out = (float*)d_out;

  // Workspace (floats): partial [16 maps * 16 groups * 16384] (16 MB) |
  // inten [16*16384] (1 MB) | tvals [160] | tidx [160 ints] | losses [8].
  float* wsf = (float*)d_ws;
  float* partial = wsf;
  float* inten = partial + (size_t)kMaps * kGroups * kHW;
  float* tvals = inten + (size_t)kMaps * kHW;
  int* tidx = (int*)(tvals + kMaps * kTopK);
  float* losses = (float*)(tidx + kMaps * kTopK);

  sumsq_kernel<<<dim3(kMaps * kGroups), dim3(512), 0, stream>>>(loc, det,
                                                                partial);
  combine_kernel<<<dim3(kMaps * kHW / 4 / 256), dim3(256), 0, stream>>>(
      partial, inten);
  topk_kernel<<<dim3(kMaps), dim3(1024), 0, stream>>>(inten, tvals, tidx);
  loss_kernel<<<dim3(kB), dim3(kC), 0, stream>>>(loc, det, tvals, tidx,
                                                 losses);
  final_kernel<<<dim3(1), dim3(64), 0, stream>>>(losses, out);
}